// Round 13
// baseline (2157.006 us; speedup 1.0000x reference)
//
#include <hip/hip_runtime.h>

#define N_TOK 16384
#define D 64
#define NC 512
#define KSEL 16
#define PADCAP 327168   // 262144 + 512*127: per-center segments padded to 128

typedef __attribute__((ext_vector_type(8))) short short8;
typedef __attribute__((ext_vector_type(16))) float float16;

__device__ __forceinline__ unsigned fkey(float f) {
    unsigned u = __float_as_uint(f);
    return (u & 0x80000000u) ? ~u : (u | 0x80000000u);
}
__device__ __forceinline__ float funkey(unsigned k) {
    unsigned u = (k & 0x80000000u) ? (k & 0x7fffffffu) : ~k;
    return __uint_as_float(u);
}
__device__ __forceinline__ unsigned short bfr(float f) {  // fp32 -> bf16 RNE
    unsigned u = __float_as_uint(f);
    return (unsigned short)((u + 0x7FFFu + ((u >> 16) & 1u)) >> 16);
}

// ---------------- kernel B: dist + top-16 + softmax (unchanged from R9) --------
__global__ __launch_bounds__(512) void topk9_kernel(
    const float* __restrict__ x, const float* __restrict__ ctrs,
    float* __restrict__ scores, int* __restrict__ sidx, int* __restrict__ hist) {
    __shared__ __align__(16) unsigned char pool[88064];
    float* xsT = (float*)pool;                  // [64 k][68]
    float* csT = (float*)(pool + 17408);        // [64 k][260] / Sb
    float* Sb  = csT;
    float* c2s = (float*)(pool + 83968);        // [512]
    int* lhist = (int*)(pool + 86016);          // [512]
    unsigned* mb = (unsigned*)(pool + 17408);   // [64][132] overlay

    const int t = threadIdx.x;
    const int lane = t & 63;
    const int wi = t >> 6;
    const int base = blockIdx.x * 64;

    lhist[t] = 0;

    {
        const float4* row = (const float4*)(ctrs + t * D);
        float s = 0.f;
        #pragma unroll
        for (int q = 0; q < 16; ++q) {
            float4 v = row[q];
            s += v.x * v.x + v.y * v.y + v.z * v.z + v.w * v.w;
        }
        c2s[t] = s;
    }

    #pragma unroll
    for (int i = 0; i < 2; ++i) {
        int e = t + 512 * i;
        int r = e >> 4, j = e & 15;
        float4 v = *(const float4*)(x + (base + r) * D + 4 * j);
        xsT[(4 * j + 0) * 68 + r] = v.x;
        xsT[(4 * j + 1) * 68 + r] = v.y;
        xsT[(4 * j + 2) * 68 + r] = v.z;
        xsT[(4 * j + 3) * 68 + r] = v.w;
    }

    unsigned run[KSEL];
    #pragma unroll
    for (int r = 0; r < KSEL; ++r) run[r] = 0u;

    #pragma unroll 1
    for (int p = 0; p < 2; ++p) {
        __syncthreads();

        #pragma unroll
        for (int i = 0; i < 8; ++i) {
            int e = t + 512 * i;
            int cl = e & 255, j = e >> 8;
            float4 v = *(const float4*)(ctrs + (p * 256 + cl) * D + 4 * j);
            csT[(4 * j + 0) * 260 + cl] = v.x;
            csT[(4 * j + 1) * 260 + cl] = v.y;
            csT[(4 * j + 2) * 260 + cl] = v.z;
            csT[(4 * j + 3) * 260 + cl] = v.w;
        }
        __syncthreads();

        float acc[8][4];
        #pragma unroll
        for (int i = 0; i < 8; ++i)
            #pragma unroll
            for (int q = 0; q < 4; ++q) acc[i][q] = 0.f;

        #pragma unroll 2
        for (int k = 0; k < 64; ++k) {
            const float* xrow = xsT + k * 68 + 8 * wi;
            float4 xa0 = *(const float4*)(xrow);
            float4 xa1 = *(const float4*)(xrow + 4);
            float4 cb = *(const float4*)(csT + k * 260 + 4 * lane);
            float xa[8] = {xa0.x, xa0.y, xa0.z, xa0.w, xa1.x, xa1.y, xa1.z, xa1.w};
            #pragma unroll
            for (int i = 0; i < 8; ++i) {
                acc[i][0] = fmaf(xa[i], cb.x, acc[i][0]);
                acc[i][1] = fmaf(xa[i], cb.y, acc[i][1]);
                acc[i][2] = fmaf(xa[i], cb.z, acc[i][2]);
                acc[i][3] = fmaf(xa[i], cb.w, acc[i][3]);
            }
        }
        __syncthreads();

        #pragma unroll
        for (int i = 0; i < 8; ++i)
            *(float4*)(Sb + lane * 260 + (8 * wi + i) * 4) =
                make_float4(acc[i][0], acc[i][1], acc[i][2], acc[i][3]);
        __syncthreads();

        #pragma unroll
        for (int s8 = 0; s8 < 8; ++s8) {
            int c4 = wi * 8 + s8;
            float4 sv = *(const float4*)(Sb + c4 * 260 + 4 * lane);
            float4 cq = *(const float4*)(c2s + p * 256 + 4 * c4);
            float sq[4] = {fmaf(2.f, sv.x, -cq.x), fmaf(2.f, sv.y, -cq.y),
                           fmaf(2.f, sv.z, -cq.z), fmaf(2.f, sv.w, -cq.w)};
            #pragma unroll
            for (int q = 0; q < 4; ++q) {
                unsigned cg = (unsigned)(p * 256 + 4 * c4 + q);
                unsigned k = (fkey(sq[q]) & 0xFFFFFE00u) | cg;
                if (k > run[KSEL - 1]) {
                    #pragma unroll
                    for (int r = 0; r < KSEL; ++r) {
                        unsigned mx = run[r] > k ? run[r] : k;
                        unsigned mn = run[r] > k ? k : run[r];
                        run[r] = mx; k = mn;
                    }
                }
            }
        }
    }

    __syncthreads();
    {
        uint4* dst = (uint4*)(mb + lane * 132 + wi * 16);
        dst[0] = make_uint4(run[0], run[1], run[2], run[3]);
        dst[1] = make_uint4(run[4], run[5], run[6], run[7]);
        dst[2] = make_uint4(run[8], run[9], run[10], run[11]);
        dst[3] = make_uint4(run[12], run[13], run[14], run[15]);
    }
    __syncthreads();

    if (wi == 0) {
        unsigned h[8]; int pos[8];
        #pragma unroll
        for (int w = 0; w < 8; ++w) { pos[w] = 0; h[w] = mb[lane * 132 + w * 16]; }
        float vals[16]; int ids[16];
        #pragma unroll
        for (int r = 0; r < KSEL; ++r) {
            unsigned m = h[0];
            #pragma unroll
            for (int w = 1; w < 8; ++w) m = m > h[w] ? m : h[w];
            vals[r] = funkey(m);
            ids[r] = (int)(m & 511u);
            #pragma unroll
            for (int w = 0; w < 8; ++w) {
                if (h[w] == m) {
                    ++pos[w];
                    h[w] = (pos[w] < KSEL) ? mb[lane * 132 + w * 16 + pos[w]] : 0u;
                }
            }
        }
        float mx = vals[0];
        float e[16]; float sum = 0.f;
        #pragma unroll
        for (int r = 0; r < KSEL; ++r) { e[r] = __expf(vals[r] - mx); sum += e[r]; }
        float inv = 1.f / sum;
        int n = base + lane;
        #pragma unroll
        for (int q = 0; q < 4; ++q) {
            *(float4*)(scores + n * KSEL + 4 * q) =
                make_float4(e[4*q] * inv, e[4*q+1] * inv, e[4*q+2] * inv, e[4*q+3] * inv);
            *(int4*)(sidx + n * KSEL + 4 * q) =
                make_int4(ids[4*q], ids[4*q+1], ids[4*q+2], ids[4*q+3]);
        }
        #pragma unroll
        for (int r = 0; r < KSEL; ++r) atomicAdd(&lhist[ids[r]], 1);
    }
    __syncthreads();
    { int hv = lhist[t]; if (hv) atomicAdd(&hist[t], hv); }
}

// ---------------- kernel S: prefix scan, segments padded to 128 ----------------
__global__ __launch_bounds__(512) void scan2_kernel(const int* __restrict__ hist,
                                                    int* __restrict__ cursor,
                                                    int* __restrict__ meta) {
    __shared__ int buf[2][NC];
    int t = threadIdx.x;
    int pad = (hist[t] + 127) & ~127;
    buf[0][t] = pad;
    __syncthreads();
    int a = 0;
    for (int d = 1; d < NC; d <<= 1) {
        int val = buf[a][t] + (t >= d ? buf[a][t - d] : 0);
        buf[1 - a][t] = val;
        __syncthreads();
        a = 1 - a;
    }
    int incl = buf[a][t];
    cursor[t] = incl - pad;
    if (t == NC - 1) meta[0] = incl;
}

// ---------------- kernel P: counting-sort scatter into padded layout ----------
// tokentab entry packs (c << 18) | e (e = token*16+slot). Pad slots stay 0
// (memset): token 0 with score 0 contributes exactly nothing downstream.
__global__ __launch_bounds__(256) void scatter4_kernel(
    const int* __restrict__ sidx, const float* __restrict__ scores,
    int* __restrict__ cursor, int* __restrict__ tokentab,
    float* __restrict__ scotab) {
    __shared__ int lh[NC];
    __shared__ int lbase[NC];
    const int t = threadIdx.x;
    for (int i = t; i < NC; i += 256) lh[i] = 0;
    __syncthreads();
    const int base_e = blockIdx.x * 1024;
    int myc[4];
    #pragma unroll
    for (int i = 0; i < 4; ++i) {
        int c = sidx[base_e + t + 256 * i];
        myc[i] = c;
        atomicAdd(&lh[c], 1);
    }
    __syncthreads();
    for (int i = t; i < NC; i += 256) {
        int h = lh[i];
        lbase[i] = h ? atomicAdd(&cursor[i], h) : 0;
        lh[i] = 0;
    }
    __syncthreads();
    #pragma unroll
    for (int i = 0; i < 4; ++i) {
        int e = base_e + t + 256 * i;
        int c = myc[i];
        int pos = lbase[c] + atomicAdd(&lh[c], 1);
        tokentab[pos] = (c << 18) | e;
        scotab[pos] = scores[e];
    }
}

// ---------------- kernel C: cooperative MFMA mix ----------------
// One 256-thread block per 128-pair single-center segment. Cooperative staging:
// Wt[p][g] bf16 (transposed W[c], staged ONCE per block), Xs[row][g] bf16
// (pre-scaled by score). Per wave: M-tile of 32 rows -> 12 ds_read_b128 +
// 8 v_mfma_f32_32x32x16_bf16, epilogue adds s*Ov and scatter-atomics.
// C-layout (verified m74/m101 + R12 pass): col=lane&31, row=(reg&3)+8*(reg>>2)+4*half.
// Stride 72 shorts = 144B: 16B-aligned b128, 4-way bank alias (~1.6x, acceptable).
__global__ __launch_bounds__(256) void mix12_kernel(
    const float* __restrict__ x, const float* __restrict__ Wv,
    const float* __restrict__ Ov, const int* __restrict__ tokentab,
    const float* __restrict__ scotab, const int* __restrict__ meta,
    float* __restrict__ out) {
    __shared__ __align__(16) unsigned short Wt[64 * 72];   //  9216 B
    __shared__ __align__(16) unsigned short Xs[128 * 72];  // 18432 B
    __shared__ int tT[128];
    __shared__ float sT[128];

    const int t = threadIdx.x;
    const int base = blockIdx.x * 128;
    if (base >= meta[0]) return;               // block-uniform, before barriers

    const int c = tokentab[base] >> 18;        // slot 0 of a segment-block

    // stage Wt[p][g]: thread t -> p = t&63, g-range [(t>>6)*16, +16)
    {
        const float* Wp = Wv + c * (D * D) + (t & 63);
        const int gb = (t >> 6) * 16;
        #pragma unroll
        for (int g = 0; g < 16; g += 2) {
            float v0 = Wp[(gb + g) * 64];
            float v1 = Wp[(gb + g + 1) * 64];
            unsigned pk = (unsigned)bfr(v0) | ((unsigned)bfr(v1) << 16);
            *(unsigned*)&Wt[(t & 63) * 72 + gb + g] = pk;
        }
    }
    // pair tables
    if (t < 128) {
        int w = tokentab[base + t];
        tT[t] = (w & 0x3FFFF) >> 4;
        sT[t] = scotab[base + t];
    }
    // stage Xs: 2 threads per row, pre-scaled by score, bf16
    {
        const int r = t >> 1;
        const int h = (t & 1) * 32;
        int wrd = tokentab[base + r];
        float s = scotab[base + r];
        int n = (wrd & 0x3FFFF) >> 4;
        const float* xp = x + n * D + h;
        #pragma unroll
        for (int q = 0; q < 8; ++q) {
            float4 v = *(const float4*)(xp + q * 4);
            unsigned p0 = (unsigned)bfr(v.x * s) | ((unsigned)bfr(v.y * s) << 16);
            unsigned p1 = (unsigned)bfr(v.z * s) | ((unsigned)bfr(v.w * s) << 16);
            *(unsigned*)&Xs[r * 72 + h + q * 4]     = p0;
            *(unsigned*)&Xs[r * 72 + h + q * 4 + 2] = p1;
        }
    }
    __syncthreads();

    const int lane = t & 63;
    const int wv = t >> 6;
    const int mrow = lane & 31;
    const int half = lane >> 5;

    float16 acc0 = {0.f,0.f,0.f,0.f,0.f,0.f,0.f,0.f,0.f,0.f,0.f,0.f,0.f,0.f,0.f,0.f};
    float16 acc1 = {0.f,0.f,0.f,0.f,0.f,0.f,0.f,0.f,0.f,0.f,0.f,0.f,0.f,0.f,0.f,0.f};

    const unsigned short* Ar = Xs + (wv * 32 + mrow) * 72;
    const unsigned short* B0 = Wt + mrow * 72;
    const unsigned short* B1 = Wt + (mrow + 32) * 72;
    #pragma unroll
    for (int kt = 0; kt < 4; ++kt) {
        short8 a  = *(const short8*)(Ar + kt * 16 + half * 8);
        short8 b0 = *(const short8*)(B0 + kt * 16 + half * 8);
        short8 b1 = *(const short8*)(B1 + kt * 16 + half * 8);
        acc0 = __builtin_amdgcn_mfma_f32_32x32x16_bf16(a, b0, acc0, 0, 0, 0);
        acc1 = __builtin_amdgcn_mfma_f32_32x32x16_bf16(a, b1, acc1, 0, 0, 0);
    }

    const float ov0 = Ov[c * D + mrow];
    const float ov1 = Ov[c * D + 32 + mrow];
    #pragma unroll
    for (int reg = 0; reg < 16; ++reg) {
        int row = wv * 32 + (reg & 3) + 8 * (reg >> 2) + 4 * half;
        int n = tT[row];
        float s = sT[row];
        unsafeAtomicAdd(out + n * D + mrow,      acc0[reg] + s * ov0);
        unsafeAtomicAdd(out + n * D + 32 + mrow, acc1[reg] + s * ov1);
    }
}

extern "C" void kernel_launch(void* const* d_in, const int* in_sizes, int n_in,
                              void* d_out, int out_size, void* d_ws, size_t ws_size,
                              hipStream_t stream) {
    const float* x    = (const float*)d_in[0];
    const float* ctrs = (const float*)d_in[1];
    const float* Wv   = (const float*)d_in[2];
    const float* Ov   = (const float*)d_in[3];
    float* out = (float*)d_out;

    int*   hist     = (int*)d_ws + 512;
    int*   meta     = (int*)d_ws + 1024;
    int*   cursor   = (int*)d_ws + 2048;
    float* scores   = (float*)d_ws + 2560;                       // 262144
    int*   sidx     = (int*)d_ws + 2560 + 262144;                // 262144
    int*   tokentab = (int*)d_ws + 2560 + 2 * 262144;            // PADCAP
    float* scotab   = (float*)d_ws + 2560 + 2 * 262144 + PADCAP; // PADCAP

    hipMemsetAsync(out, 0, (size_t)N_TOK * D * sizeof(float), stream);
    hipMemsetAsync(hist, 0, NC * sizeof(int), stream);
    hipMemsetAsync(tokentab, 0, (size_t)PADCAP * sizeof(int), stream);
    hipMemsetAsync(scotab, 0, (size_t)PADCAP * sizeof(float), stream);
    hipLaunchKernelGGL(topk9_kernel, dim3(N_TOK / 64), dim3(512), 0, stream,
                       x, ctrs, scores, sidx, hist);
    hipLaunchKernelGGL(scan2_kernel, dim3(1), dim3(512), 0, stream, hist, cursor, meta);
    hipLaunchKernelGGL(scatter4_kernel, dim3(256), dim3(256), 0, stream,
                       sidx, scores, cursor, tokentab, scotab);
    hipLaunchKernelGGL(mix12_kernel, dim3(PADCAP / 128), dim3(256), 0, stream,
                       x, Wv, Ov, tokentab, scotab, meta, out);
}

// Round 14
// 195.759 us; speedup vs baseline: 11.0187x; 11.0187x over previous
//
#include <hip/hip_runtime.h>

#define N_TOK 16384
#define D 64
#define NC 512
#define KSEL 16
#define PADCAP 327168   // 262144 + 512*127: per-center segments padded to 128

typedef __attribute__((ext_vector_type(8))) short short8;
typedef __attribute__((ext_vector_type(16))) float float16;

__device__ __forceinline__ unsigned fkey(float f) {
    unsigned u = __float_as_uint(f);
    return (u & 0x80000000u) ? ~u : (u | 0x80000000u);
}
__device__ __forceinline__ float funkey(unsigned k) {
    unsigned u = (k & 0x80000000u) ? (k & 0x7fffffffu) : ~k;
    return __uint_as_float(u);
}
__device__ __forceinline__ unsigned short bfr(float f) {  // fp32 -> bf16 RNE
    unsigned u = __float_as_uint(f);
    return (unsigned short)((u + 0x7FFFu + ((u >> 16) & 1u)) >> 16);
}

// ---------------- kernel B: dist + top-16 + softmax (unchanged from R9) --------
__global__ __launch_bounds__(512) void topk9_kernel(
    const float* __restrict__ x, const float* __restrict__ ctrs,
    float* __restrict__ scores, int* __restrict__ sidx, int* __restrict__ hist) {
    __shared__ __align__(16) unsigned char pool[88064];
    float* xsT = (float*)pool;                  // [64 k][68]
    float* csT = (float*)(pool + 17408);        // [64 k][260] / Sb
    float* Sb  = csT;
    float* c2s = (float*)(pool + 83968);        // [512]
    int* lhist = (int*)(pool + 86016);          // [512]
    unsigned* mb = (unsigned*)(pool + 17408);   // [64][132] overlay

    const int t = threadIdx.x;
    const int lane = t & 63;
    const int wi = t >> 6;
    const int base = blockIdx.x * 64;

    lhist[t] = 0;

    {
        const float4* row = (const float4*)(ctrs + t * D);
        float s = 0.f;
        #pragma unroll
        for (int q = 0; q < 16; ++q) {
            float4 v = row[q];
            s += v.x * v.x + v.y * v.y + v.z * v.z + v.w * v.w;
        }
        c2s[t] = s;
    }

    #pragma unroll
    for (int i = 0; i < 2; ++i) {
        int e = t + 512 * i;
        int r = e >> 4, j = e & 15;
        float4 v = *(const float4*)(x + (base + r) * D + 4 * j);
        xsT[(4 * j + 0) * 68 + r] = v.x;
        xsT[(4 * j + 1) * 68 + r] = v.y;
        xsT[(4 * j + 2) * 68 + r] = v.z;
        xsT[(4 * j + 3) * 68 + r] = v.w;
    }

    unsigned run[KSEL];
    #pragma unroll
    for (int r = 0; r < KSEL; ++r) run[r] = 0u;

    #pragma unroll 1
    for (int p = 0; p < 2; ++p) {
        __syncthreads();

        #pragma unroll
        for (int i = 0; i < 8; ++i) {
            int e = t + 512 * i;
            int cl = e & 255, j = e >> 8;
            float4 v = *(const float4*)(ctrs + (p * 256 + cl) * D + 4 * j);
            csT[(4 * j + 0) * 260 + cl] = v.x;
            csT[(4 * j + 1) * 260 + cl] = v.y;
            csT[(4 * j + 2) * 260 + cl] = v.z;
            csT[(4 * j + 3) * 260 + cl] = v.w;
        }
        __syncthreads();

        float acc[8][4];
        #pragma unroll
        for (int i = 0; i < 8; ++i)
            #pragma unroll
            for (int q = 0; q < 4; ++q) acc[i][q] = 0.f;

        #pragma unroll 2
        for (int k = 0; k < 64; ++k) {
            const float* xrow = xsT + k * 68 + 8 * wi;
            float4 xa0 = *(const float4*)(xrow);
            float4 xa1 = *(const float4*)(xrow + 4);
            float4 cb = *(const float4*)(csT + k * 260 + 4 * lane);
            float xa[8] = {xa0.x, xa0.y, xa0.z, xa0.w, xa1.x, xa1.y, xa1.z, xa1.w};
            #pragma unroll
            for (int i = 0; i < 8; ++i) {
                acc[i][0] = fmaf(xa[i], cb.x, acc[i][0]);
                acc[i][1] = fmaf(xa[i], cb.y, acc[i][1]);
                acc[i][2] = fmaf(xa[i], cb.z, acc[i][2]);
                acc[i][3] = fmaf(xa[i], cb.w, acc[i][3]);
            }
        }
        __syncthreads();

        #pragma unroll
        for (int i = 0; i < 8; ++i)
            *(float4*)(Sb + lane * 260 + (8 * wi + i) * 4) =
                make_float4(acc[i][0], acc[i][1], acc[i][2], acc[i][3]);
        __syncthreads();

        #pragma unroll
        for (int s8 = 0; s8 < 8; ++s8) {
            int c4 = wi * 8 + s8;
            float4 sv = *(const float4*)(Sb + c4 * 260 + 4 * lane);
            float4 cq = *(const float4*)(c2s + p * 256 + 4 * c4);
            float sq[4] = {fmaf(2.f, sv.x, -cq.x), fmaf(2.f, sv.y, -cq.y),
                           fmaf(2.f, sv.z, -cq.z), fmaf(2.f, sv.w, -cq.w)};
            #pragma unroll
            for (int q = 0; q < 4; ++q) {
                unsigned cg = (unsigned)(p * 256 + 4 * c4 + q);
                unsigned k = (fkey(sq[q]) & 0xFFFFFE00u) | cg;
                if (k > run[KSEL - 1]) {
                    #pragma unroll
                    for (int r = 0; r < KSEL; ++r) {
                        unsigned mx = run[r] > k ? run[r] : k;
                        unsigned mn = run[r] > k ? k : run[r];
                        run[r] = mx; k = mn;
                    }
                }
            }
        }
    }

    __syncthreads();
    {
        uint4* dst = (uint4*)(mb + lane * 132 + wi * 16);
        dst[0] = make_uint4(run[0], run[1], run[2], run[3]);
        dst[1] = make_uint4(run[4], run[5], run[6], run[7]);
        dst[2] = make_uint4(run[8], run[9], run[10], run[11]);
        dst[3] = make_uint4(run[12], run[13], run[14], run[15]);
    }
    __syncthreads();

    if (wi == 0) {
        unsigned h[8]; int pos[8];
        #pragma unroll
        for (int w = 0; w < 8; ++w) { pos[w] = 0; h[w] = mb[lane * 132 + w * 16]; }
        float vals[16]; int ids[16];
        #pragma unroll
        for (int r = 0; r < KSEL; ++r) {
            unsigned m = h[0];
            #pragma unroll
            for (int w = 1; w < 8; ++w) m = m > h[w] ? m : h[w];
            vals[r] = funkey(m);
            ids[r] = (int)(m & 511u);
            #pragma unroll
            for (int w = 0; w < 8; ++w) {
                if (h[w] == m) {
                    ++pos[w];
                    h[w] = (pos[w] < KSEL) ? mb[lane * 132 + w * 16 + pos[w]] : 0u;
                }
            }
        }
        float mx = vals[0];
        float e[16]; float sum = 0.f;
        #pragma unroll
        for (int r = 0; r < KSEL; ++r) { e[r] = __expf(vals[r] - mx); sum += e[r]; }
        float inv = 1.f / sum;
        int n = base + lane;
        #pragma unroll
        for (int q = 0; q < 4; ++q) {
            *(float4*)(scores + n * KSEL + 4 * q) =
                make_float4(e[4*q] * inv, e[4*q+1] * inv, e[4*q+2] * inv, e[4*q+3] * inv);
            *(int4*)(sidx + n * KSEL + 4 * q) =
                make_int4(ids[4*q], ids[4*q+1], ids[4*q+2], ids[4*q+3]);
        }
        #pragma unroll
        for (int r = 0; r < KSEL; ++r) atomicAdd(&lhist[ids[r]], 1);
    }
    __syncthreads();
    { int hv = lhist[t]; if (hv) atomicAdd(&hist[t], hv); }
}

// ---------------- kernel S: prefix scan, segments padded to 128 ----------------
__global__ __launch_bounds__(512) void scan2_kernel(const int* __restrict__ hist,
                                                    int* __restrict__ cursor,
                                                    int* __restrict__ meta) {
    __shared__ int buf[2][NC];
    int t = threadIdx.x;
    int pad = (hist[t] + 127) & ~127;
    buf[0][t] = pad;
    __syncthreads();
    int a = 0;
    for (int d = 1; d < NC; d <<= 1) {
        int val = buf[a][t] + (t >= d ? buf[a][t - d] : 0);
        buf[1 - a][t] = val;
        __syncthreads();
        a = 1 - a;
    }
    int incl = buf[a][t];
    cursor[t] = incl - pad;
    if (t == NC - 1) meta[0] = incl;
}

// ---------------- kernel P: counting-sort scatter into padded layout ----------
// tokentab entry packs (c << 18) | e (e = token*16+slot). Pad slots stay 0
// (memset): score 0 -> skipped in mix epilogue.
__global__ __launch_bounds__(256) void scatter4_kernel(
    const int* __restrict__ sidx, const float* __restrict__ scores,
    int* __restrict__ cursor, int* __restrict__ tokentab,
    float* __restrict__ scotab) {
    __shared__ int lh[NC];
    __shared__ int lbase[NC];
    const int t = threadIdx.x;
    for (int i = t; i < NC; i += 256) lh[i] = 0;
    __syncthreads();
    const int base_e = blockIdx.x * 1024;
    int myc[4];
    #pragma unroll
    for (int i = 0; i < 4; ++i) {
        int c = sidx[base_e + t + 256 * i];
        myc[i] = c;
        atomicAdd(&lh[c], 1);
    }
    __syncthreads();
    for (int i = t; i < NC; i += 256) {
        int h = lh[i];
        lbase[i] = h ? atomicAdd(&cursor[i], h) : 0;
        lh[i] = 0;
    }
    __syncthreads();
    #pragma unroll
    for (int i = 0; i < 4; ++i) {
        int e = base_e + t + 256 * i;
        int c = myc[i];
        int pos = lbase[c] + atomicAdd(&lh[c], 1);
        tokentab[pos] = (c << 18) | e;
        scotab[pos] = scores[e];
    }
}

// ---------------- kernel C: cooperative MFMA mix (pad-atomics SKIPPED) --------
// One 256-thread block per 128-pair single-center segment. Cooperative staging:
// Wt[p][g] bf16 (transposed W[c], once per block), Xs[row][g] bf16 (pre-scaled).
// Per wave: 12 ds_read_b128 + 8 v_mfma_f32_32x32x16_bf16; epilogue adds s*Ov and
// scatter-atomics — GUARDED by s!=0: pad rows (score 0) issue NO atomics.
// (R13 lesson: 32K pad rows x 64 cols of same-address atomics on out[0][:] was
// the 2 ms. Skipping is exact: their contribution is identically +0.0.)
__global__ __launch_bounds__(256) void mix13_kernel(
    const float* __restrict__ x, const float* __restrict__ Wv,
    const float* __restrict__ Ov, const int* __restrict__ tokentab,
    const float* __restrict__ scotab, const int* __restrict__ meta,
    float* __restrict__ out) {
    __shared__ __align__(16) unsigned short Wt[64 * 72];   //  9216 B
    __shared__ __align__(16) unsigned short Xs[128 * 72];  // 18432 B
    __shared__ int tT[128];
    __shared__ float sT[128];

    const int t = threadIdx.x;
    const int base = blockIdx.x * 128;
    if (base >= meta[0]) return;               // block-uniform, before barriers

    const int c = tokentab[base] >> 18;        // slot 0 of a segment-block is real

    // stage Wt[p][g]: thread t -> p = t&63, g-range [(t>>6)*16, +16)
    {
        const float* Wp = Wv + c * (D * D) + (t & 63);
        const int gb = (t >> 6) * 16;
        #pragma unroll
        for (int g = 0; g < 16; g += 2) {
            float v0 = Wp[(gb + g) * 64];
            float v1 = Wp[(gb + g + 1) * 64];
            unsigned pk = (unsigned)bfr(v0) | ((unsigned)bfr(v1) << 16);
            *(unsigned*)&Wt[(t & 63) * 72 + gb + g] = pk;
        }
    }
    // pair tables
    if (t < 128) {
        int w = tokentab[base + t];
        tT[t] = (w & 0x3FFFF) >> 4;
        sT[t] = scotab[base + t];
    }
    // stage Xs: 2 threads per row, pre-scaled by score, bf16
    {
        const int r = t >> 1;
        const int h = (t & 1) * 32;
        int wrd = tokentab[base + r];
        float s = scotab[base + r];
        int n = (wrd & 0x3FFFF) >> 4;
        const float* xp = x + n * D + h;
        #pragma unroll
        for (int q = 0; q < 8; ++q) {
            float4 v = *(const float4*)(xp + q * 4);
            unsigned p0 = (unsigned)bfr(v.x * s) | ((unsigned)bfr(v.y * s) << 16);
            unsigned p1 = (unsigned)bfr(v.z * s) | ((unsigned)bfr(v.w * s) << 16);
            *(unsigned*)&Xs[r * 72 + h + q * 4]     = p0;
            *(unsigned*)&Xs[r * 72 + h + q * 4 + 2] = p1;
        }
    }
    __syncthreads();

    const int lane = t & 63;
    const int wv = t >> 6;
    const int mrow = lane & 31;
    const int half = lane >> 5;

    float16 acc0 = {0.f,0.f,0.f,0.f,0.f,0.f,0.f,0.f,0.f,0.f,0.f,0.f,0.f,0.f,0.f,0.f};
    float16 acc1 = {0.f,0.f,0.f,0.f,0.f,0.f,0.f,0.f,0.f,0.f,0.f,0.f,0.f,0.f,0.f,0.f};

    const unsigned short* Ar = Xs + (wv * 32 + mrow) * 72;
    const unsigned short* B0 = Wt + mrow * 72;
    const unsigned short* B1 = Wt + (mrow + 32) * 72;
    #pragma unroll
    for (int kt = 0; kt < 4; ++kt) {
        short8 a  = *(const short8*)(Ar + kt * 16 + half * 8);
        short8 b0 = *(const short8*)(B0 + kt * 16 + half * 8);
        short8 b1 = *(const short8*)(B1 + kt * 16 + half * 8);
        acc0 = __builtin_amdgcn_mfma_f32_32x32x16_bf16(a, b0, acc0, 0, 0, 0);
        acc1 = __builtin_amdgcn_mfma_f32_32x32x16_bf16(a, b1, acc1, 0, 0, 0);
    }

    const float ov0 = Ov[c * D + mrow];
    const float ov1 = Ov[c * D + 32 + mrow];
    #pragma unroll
    for (int reg = 0; reg < 16; ++reg) {
        int row = wv * 32 + (reg & 3) + 8 * (reg >> 2) + 4 * half;
        float s = sT[row];
        if (s != 0.f) {                        // pad rows: no atomics
            int n = tT[row];
            unsafeAtomicAdd(out + n * D + mrow,      acc0[reg] + s * ov0);
            unsafeAtomicAdd(out + n * D + 32 + mrow, acc1[reg] + s * ov1);
        }
    }
}

extern "C" void kernel_launch(void* const* d_in, const int* in_sizes, int n_in,
                              void* d_out, int out_size, void* d_ws, size_t ws_size,
                              hipStream_t stream) {
    const float* x    = (const float*)d_in[0];
    const float* ctrs = (const float*)d_in[1];
    const float* Wv   = (const float*)d_in[2];
    const float* Ov   = (const float*)d_in[3];
    float* out = (float*)d_out;

    int*   hist     = (int*)d_ws + 512;
    int*   meta     = (int*)d_ws + 1024;
    int*   cursor   = (int*)d_ws + 2048;
    float* scores   = (float*)d_ws + 2560;                       // 262144
    int*   sidx     = (int*)d_ws + 2560 + 262144;                // 262144
    int*   tokentab = (int*)d_ws + 2560 + 2 * 262144;            // PADCAP
    float* scotab   = (float*)d_ws + 2560 + 2 * 262144 + PADCAP; // PADCAP

    hipMemsetAsync(out, 0, (size_t)N_TOK * D * sizeof(float), stream);
    hipMemsetAsync(hist, 0, NC * sizeof(int), stream);
    hipMemsetAsync(tokentab, 0, (size_t)PADCAP * sizeof(int), stream);
    hipMemsetAsync(scotab, 0, (size_t)PADCAP * sizeof(float), stream);
    hipLaunchKernelGGL(topk9_kernel, dim3(N_TOK / 64), dim3(512), 0, stream,
                       x, ctrs, scores, sidx, hist);
    hipLaunchKernelGGL(scan2_kernel, dim3(1), dim3(512), 0, stream, hist, cursor, meta);
    hipLaunchKernelGGL(scatter4_kernel, dim3(256), dim3(256), 0, stream,
                       sidx, scores, cursor, tokentab, scotab);
    hipLaunchKernelGGL(mix13_kernel, dim3(PADCAP / 128), dim3(256), 0, stream,
                       x, Wv, Ov, tokentab, scotab, meta, out);
}

// Round 15
// 193.373 us; speedup vs baseline: 11.1547x; 1.0123x over previous
//
#include <hip/hip_runtime.h>

#define N_TOK 16384
#define D 64
#define NC 512
#define KSEL 16
#define PADCAP 327168   // 262144 + 512*127: per-center segments padded to 128

typedef __attribute__((ext_vector_type(8))) short short8;
typedef __attribute__((ext_vector_type(16))) float float16;

__device__ __forceinline__ unsigned fkey(float f) {
    unsigned u = __float_as_uint(f);
    return (u & 0x80000000u) ? ~u : (u | 0x80000000u);
}
__device__ __forceinline__ float funkey(unsigned k) {
    unsigned u = (k & 0x80000000u) ? (k & 0x7fffffffu) : ~k;
    return __uint_as_float(u);
}
__device__ __forceinline__ unsigned short bfr(float f) {  // fp32 -> bf16 RNE
    unsigned u = __float_as_uint(f);
    return (unsigned short)((u + 0x7FFFu + ((u >> 16) & 1u)) >> 16);
}

// ---------------- kernel B: dist + top-16 + softmax ----------------
// topk9 re-tiled to 128-center phases: LDS 55.3 KB -> 2 blocks/CU (was 1 at 88KB).
// 512 threads = 8 waves; thread (wi, lane) computes 4 tokens x 4 centers per k:
// tokens 8*wi + (lane>>5)*4 ..+4, centers 4*(lane&31) ..+4 of the phase.
// Register prefetch of next phase's centers overlaps compute.
__global__ __launch_bounds__(512) void topk10_kernel(
    const float* __restrict__ x, const float* __restrict__ ctrs,
    float* __restrict__ scores, int* __restrict__ sidx, int* __restrict__ hist) {
    __shared__ __align__(16) unsigned char pool[55296];
    float* xsT = (float*)pool;                  // [64 k][68]   17408 B
    float* csT = (float*)(pool + 17408);        // [64 k][132]  33792 B
    float* Sb  = csT;                           // Sb[c4][tok*4+q], stride 260 (32 rows)
    float* c2s = (float*)(pool + 51200);        // [512]         2048 B
    int* lhist = (int*)(pool + 53248);          // [512]         2048 B
    unsigned* mb = (unsigned*)(pool + 17408);   // [64][132] overlay on csT/Sb

    const int t = threadIdx.x;
    const int lane = t & 63;
    const int wi = t >> 6;
    const int base = blockIdx.x * 64;

    lhist[t] = 0;

    // c2: thread t computes ||ctrs[t]||^2
    {
        const float4* row = (const float4*)(ctrs + t * D);
        float s = 0.f;
        #pragma unroll
        for (int q = 0; q < 16; ++q) {
            float4 v = row[q];
            s += v.x * v.x + v.y * v.y + v.z * v.z + v.w * v.w;
        }
        c2s[t] = s;
    }

    // stage xsT[k][tok]
    #pragma unroll
    for (int i = 0; i < 2; ++i) {
        int e = t + 512 * i;
        int r = e >> 4, j = e & 15;
        float4 v = *(const float4*)(x + (base + r) * D + 4 * j);
        xsT[(4 * j + 0) * 68 + r] = v.x;
        xsT[(4 * j + 1) * 68 + r] = v.y;
        xsT[(4 * j + 2) * 68 + r] = v.z;
        xsT[(4 * j + 3) * 68 + r] = v.w;
    }

    unsigned run[KSEL];
    #pragma unroll
    for (int r = 0; r < KSEL; ++r) run[r] = 0u;

    // prefetch phase-0 centers: 128 x 64 floats / 512 threads = 4 float4 each
    float4 pre[4];
    #pragma unroll
    for (int i = 0; i < 4; ++i) {
        int e = t + 512 * i;
        int cl = e >> 4, j = e & 15;
        pre[i] = *(const float4*)(ctrs + cl * D + 4 * j);
    }

    const int tokq = (lane >> 5) * 4;   // 0 or 4
    const int c4 = lane & 31;

    #pragma unroll 1
    for (int p = 0; p < 4; ++p) {
        __syncthreads();   // prev phase's Sb reads done (p=0: xsT/c2s ready)
        #pragma unroll
        for (int i = 0; i < 4; ++i) {
            int e = t + 512 * i;
            int cl = e >> 4, j = e & 15;
            csT[(4 * j + 0) * 132 + cl] = pre[i].x;
            csT[(4 * j + 1) * 132 + cl] = pre[i].y;
            csT[(4 * j + 2) * 132 + cl] = pre[i].z;
            csT[(4 * j + 3) * 132 + cl] = pre[i].w;
        }
        if (p < 3) {
            #pragma unroll
            for (int i = 0; i < 4; ++i) {
                int e = t + 512 * i;
                int cl = e >> 4, j = e & 15;
                pre[i] = *(const float4*)(ctrs + ((p + 1) * 128 + cl) * D + 4 * j);
            }
        }
        __syncthreads();

        float acc[4][4];
        #pragma unroll
        for (int i = 0; i < 4; ++i)
            #pragma unroll
            for (int q = 0; q < 4; ++q) acc[i][q] = 0.f;

        #pragma unroll 2
        for (int k = 0; k < 64; ++k) {
            float4 xa = *(const float4*)(xsT + k * 68 + 8 * wi + tokq);
            float4 cb = *(const float4*)(csT + k * 132 + 4 * c4);
            float xv[4] = {xa.x, xa.y, xa.z, xa.w};
            #pragma unroll
            for (int i = 0; i < 4; ++i) {
                acc[i][0] = fmaf(xv[i], cb.x, acc[i][0]);
                acc[i][1] = fmaf(xv[i], cb.y, acc[i][1]);
                acc[i][2] = fmaf(xv[i], cb.z, acc[i][2]);
                acc[i][3] = fmaf(xv[i], cb.w, acc[i][3]);
            }
        }
        __syncthreads();   // csT reads done -> Sb overlay safe

        #pragma unroll
        for (int i = 0; i < 4; ++i)
            *(float4*)(Sb + c4 * 260 + (8 * wi + tokq + i) * 4) =
                make_float4(acc[i][0], acc[i][1], acc[i][2], acc[i][3]);
        __syncthreads();

        // selection: wave wi handles c4 slice [4wi, 4wi+4); token = lane
        #pragma unroll
        for (int s4 = 0; s4 < 4; ++s4) {
            int cc = wi * 4 + s4;
            float4 sv = *(const float4*)(Sb + cc * 260 + 4 * lane);
            float4 cq = *(const float4*)(c2s + p * 128 + 4 * cc);  // uniform
            float sq[4] = {fmaf(2.f, sv.x, -cq.x), fmaf(2.f, sv.y, -cq.y),
                           fmaf(2.f, sv.z, -cq.z), fmaf(2.f, sv.w, -cq.w)};
            #pragma unroll
            for (int q = 0; q < 4; ++q) {
                unsigned cg = (unsigned)(p * 128 + 4 * cc + q);
                unsigned k = (fkey(sq[q]) & 0xFFFFFE00u) | cg;
                if (k > run[KSEL - 1]) {
                    #pragma unroll
                    for (int r = 0; r < KSEL; ++r) {
                        unsigned mx = run[r] > k ? run[r] : k;
                        unsigned mn = run[r] > k ? k : run[r];
                        run[r] = mx; k = mn;
                    }
                }
            }
        }
    }

    __syncthreads();   // Sb reads done -> mb overlay safe
    {
        uint4* dst = (uint4*)(mb + lane * 132 + wi * 16);
        dst[0] = make_uint4(run[0], run[1], run[2], run[3]);
        dst[1] = make_uint4(run[4], run[5], run[6], run[7]);
        dst[2] = make_uint4(run[8], run[9], run[10], run[11]);
        dst[3] = make_uint4(run[12], run[13], run[14], run[15]);
    }
    __syncthreads();

    if (wi == 0) {  // 8-way tournament merge per lane (= per token), exact
        unsigned h[8]; int pos[8];
        #pragma unroll
        for (int w = 0; w < 8; ++w) { pos[w] = 0; h[w] = mb[lane * 132 + w * 16]; }
        float vals[16]; int ids[16];
        #pragma unroll
        for (int r = 0; r < KSEL; ++r) {
            unsigned m = h[0];
            #pragma unroll
            for (int w = 1; w < 8; ++w) m = m > h[w] ? m : h[w];
            vals[r] = funkey(m);
            ids[r] = (int)(m & 511u);
            #pragma unroll
            for (int w = 0; w < 8; ++w) {
                if (h[w] == m) {
                    ++pos[w];
                    h[w] = (pos[w] < KSEL) ? mb[lane * 132 + w * 16 + pos[w]] : 0u;
                }
            }
        }
        float mx = vals[0];
        float e[16]; float sum = 0.f;
        #pragma unroll
        for (int r = 0; r < KSEL; ++r) { e[r] = __expf(vals[r] - mx); sum += e[r]; }
        float inv = 1.f / sum;
        int n = base + lane;
        #pragma unroll
        for (int q = 0; q < 4; ++q) {
            *(float4*)(scores + n * KSEL + 4 * q) =
                make_float4(e[4*q] * inv, e[4*q+1] * inv, e[4*q+2] * inv, e[4*q+3] * inv);
            *(int4*)(sidx + n * KSEL + 4 * q) =
                make_int4(ids[4*q], ids[4*q+1], ids[4*q+2], ids[4*q+3]);
        }
        #pragma unroll
        for (int r = 0; r < KSEL; ++r) atomicAdd(&lhist[ids[r]], 1);
    }
    __syncthreads();
    { int hv = lhist[t]; if (hv) atomicAdd(&hist[t], hv); }
}

// ---------------- kernel S: prefix scan, segments padded to 128 ----------------
__global__ __launch_bounds__(512) void scan2_kernel(const int* __restrict__ hist,
                                                    int* __restrict__ cursor,
                                                    int* __restrict__ meta) {
    __shared__ int buf[2][NC];
    int t = threadIdx.x;
    int pad = (hist[t] + 127) & ~127;
    buf[0][t] = pad;
    __syncthreads();
    int a = 0;
    for (int d = 1; d < NC; d <<= 1) {
        int val = buf[a][t] + (t >= d ? buf[a][t - d] : 0);
        buf[1 - a][t] = val;
        __syncthreads();
        a = 1 - a;
    }
    int incl = buf[a][t];
    cursor[t] = incl - pad;
    if (t == NC - 1) meta[0] = incl;
}

// ---------------- kernel P: counting-sort scatter into padded layout ----------
__global__ __launch_bounds__(256) void scatter4_kernel(
    const int* __restrict__ sidx, const float* __restrict__ scores,
    int* __restrict__ cursor, int* __restrict__ tokentab,
    float* __restrict__ scotab) {
    __shared__ int lh[NC];
    __shared__ int lbase[NC];
    const int t = threadIdx.x;
    for (int i = t; i < NC; i += 256) lh[i] = 0;
    __syncthreads();
    const int base_e = blockIdx.x * 1024;
    int myc[4];
    #pragma unroll
    for (int i = 0; i < 4; ++i) {
        int c = sidx[base_e + t + 256 * i];
        myc[i] = c;
        atomicAdd(&lh[c], 1);
    }
    __syncthreads();
    for (int i = t; i < NC; i += 256) {
        int h = lh[i];
        lbase[i] = h ? atomicAdd(&cursor[i], h) : 0;
        lh[i] = 0;
    }
    __syncthreads();
    #pragma unroll
    for (int i = 0; i < 4; ++i) {
        int e = base_e + t + 256 * i;
        int c = myc[i];
        int pos = lbase[c] + atomicAdd(&lh[c], 1);
        tokentab[pos] = (c << 18) | e;
        scotab[pos] = scores[e];
    }
}

// ---------------- kernel C: MFMA mix, W in LDS, X gathered direct -------------
// One 256-thread block per 128-pair segment. Only W is LDS-staged (10.4 KB ->
// high occupancy); each lane gathers its own token's k-slice straight from
// global (L3-resident), scales by score, packs bf16 in registers. 8 MFMAs,
// epilogue atomics guarded by s!=0 (pad rows silent).
__global__ __launch_bounds__(256) void mix14_kernel(
    const float* __restrict__ x, const float* __restrict__ Wv,
    const float* __restrict__ Ov, const int* __restrict__ tokentab,
    const float* __restrict__ scotab, const int* __restrict__ meta,
    float* __restrict__ out) {
    __shared__ __align__(16) unsigned short Wt[64 * 72];   // 9216 B
    __shared__ int tT[128];
    __shared__ float sT[128];

    const int t = threadIdx.x;
    const int base = blockIdx.x * 128;
    if (base >= meta[0]) return;               // block-uniform, before barriers

    const int c = tokentab[base] >> 18;

    // stage Wt[p][g]: thread t -> p = t&63, g-range [(t>>6)*16, +16)
    {
        const float* Wp = Wv + c * (D * D) + (t & 63);
        const int gb = (t >> 6) * 16;
        #pragma unroll
        for (int g = 0; g < 16; g += 2) {
            float v0 = Wp[(gb + g) * 64];
            float v1 = Wp[(gb + g + 1) * 64];
            unsigned pk = (unsigned)bfr(v0) | ((unsigned)bfr(v1) << 16);
            *(unsigned*)&Wt[(t & 63) * 72 + gb + g] = pk;
        }
    }
    if (t < 128) {
        int w = tokentab[base + t];
        tT[t] = (w & 0x3FFFF) >> 4;
        sT[t] = scotab[base + t];
    }
    __syncthreads();

    const int lane = t & 63;
    const int wv = t >> 6;
    const int mrow = lane & 31;
    const int half = lane >> 5;
    const int row = wv * 32 + mrow;

    const int   myn = tT[row];
    const float mys = sT[row];

    // gather own token's k-slices: k = kt*16 + half*8 + j
    const float* xp = x + myn * D + half * 8;
    float4 f[8];
    #pragma unroll
    for (int kt = 0; kt < 4; ++kt) {
        f[2 * kt]     = *(const float4*)(xp + kt * 16);
        f[2 * kt + 1] = *(const float4*)(xp + kt * 16 + 4);
    }
    short8 a[4];
    #pragma unroll
    for (int kt = 0; kt < 4; ++kt) {
        float4 u = f[2 * kt], v = f[2 * kt + 1];
        a[kt][0] = (short)bfr(u.x * mys); a[kt][1] = (short)bfr(u.y * mys);
        a[kt][2] = (short)bfr(u.z * mys); a[kt][3] = (short)bfr(u.w * mys);
        a[kt][4] = (short)bfr(v.x * mys); a[kt][5] = (short)bfr(v.y * mys);
        a[kt][6] = (short)bfr(v.z * mys); a[kt][7] = (short)bfr(v.w * mys);
    }

    float16 acc0 = {0.f,0.f,0.f,0.f,0.f,0.f,0.f,0.f,0.f,0.f,0.f,0.f,0.f,0.f,0.f,0.f};
    float16 acc1 = {0.f,0.f,0.f,0.f,0.f,0.f,0.f,0.f,0.f,0.f,0.f,0.f,0.f,0.f,0.f,0.f};

    const unsigned short* B0 = Wt + mrow * 72;
    const unsigned short* B1 = Wt + (mrow + 32) * 72;
    #pragma unroll
    for (int kt = 0; kt < 4; ++kt) {
        short8 b0 = *(const short8*)(B0 + kt * 16 + half * 8);
        short8 b1 = *(const short8*)(B1 + kt * 16 + half * 8);
        acc0 = __builtin_amdgcn_mfma_f32_32x32x16_bf16(a[kt], b0, acc0, 0, 0, 0);
        acc1 = __builtin_amdgcn_mfma_f32_32x32x16_bf16(a[kt], b1, acc1, 0, 0, 0);
    }

    const float ov0 = Ov[c * D + mrow];
    const float ov1 = Ov[c * D + 32 + mrow];
    #pragma unroll
    for (int reg = 0; reg < 16; ++reg) {
        int orow = wv * 32 + (reg & 3) + 8 * (reg >> 2) + 4 * half;
        float s = sT[orow];
        if (s != 0.f) {                        // pad rows: no atomics
            int n = tT[orow];
            unsafeAtomicAdd(out + n * D + mrow,      acc0[reg] + s * ov0);
            unsafeAtomicAdd(out + n * D + 32 + mrow, acc1[reg] + s * ov1);
        }
    }
}

extern "C" void kernel_launch(void* const* d_in, const int* in_sizes, int n_in,
                              void* d_out, int out_size, void* d_ws, size_t ws_size,
                              hipStream_t stream) {
    const float* x    = (const float*)d_in[0];
    const float* ctrs = (const float*)d_in[1];
    const float* Wv   = (const float*)d_in[2];
    const float* Ov   = (const float*)d_in[3];
    float* out = (float*)d_out;

    int*   hist     = (int*)d_ws + 512;
    int*   meta     = (int*)d_ws + 1024;
    int*   cursor   = (int*)d_ws + 2048;
    float* scores   = (float*)d_ws + 2560;                       // 262144
    int*   sidx     = (int*)d_ws + 2560 + 262144;                // 262144
    int*   tokentab = (int*)d_ws + 2560 + 2 * 262144;            // PADCAP
    float* scotab   = (float*)d_ws + 2560 + 2 * 262144 + PADCAP; // PADCAP

    hipMemsetAsync(out, 0, (size_t)N_TOK * D * sizeof(float), stream);
    hipMemsetAsync(hist, 0, NC * sizeof(int), stream);
    hipMemsetAsync(tokentab, 0, (size_t)PADCAP * sizeof(int), stream);
    hipMemsetAsync(scotab, 0, (size_t)PADCAP * sizeof(float), stream);
    hipLaunchKernelGGL(topk10_kernel, dim3(N_TOK / 64), dim3(512), 0, stream,
                       x, ctrs, scores, sidx, hist);
    hipLaunchKernelGGL(scan2_kernel, dim3(1), dim3(512), 0, stream, hist, cursor, meta);
    hipLaunchKernelGGL(scatter4_kernel, dim3(256), dim3(256), 0, stream,
                       sidx, scores, cursor, tokentab, scotab);
    hipLaunchKernelGGL(mix14_kernel, dim3(PADCAP / 128), dim3(256), 0, stream,
                       x, Wv, Ov, tokentab, scotab, meta, out);
}